// Round 9
// baseline (387.857 us; speedup 1.0000x reference)
//
#include <hip/hip_runtime.h>
#include <float.h>
#include <limits.h>

// Problem constants
#define BB 16384   // batch rows
#define DIN 1024   // encoder input dim
#define CB 512     // codebook dim
#define KC 1024    // codewords per layer
#define NL 4       // layers

// Refine margin: fp16 1-term distance noise std ~0.022, max ~0.13.
// 0.25 = ~8 sigma AND >= 2x max single-value error (certainty bound).
#define DELTA 0.25f

typedef __attribute__((ext_vector_type(8))) _Float16 half8;
typedef __attribute__((ext_vector_type(8))) short bf16x8;
typedef __attribute__((ext_vector_type(8))) unsigned short us8;
typedef __attribute__((ext_vector_type(4))) float f32x4;

__device__ __forceinline__ unsigned short f2h(float f) {
  _Float16 h = (_Float16)f;  // RTN
  return *(unsigned short*)&h;
}

// fp32 -> bf16 RTNE (wsplit only)
__device__ __forceinline__ unsigned short f2b(float f) {
  unsigned u = __float_as_uint(f);
  unsigned r = u + 0x7fffu + ((u >> 16) & 1u);
  return (unsigned short)(r >> 16);
}
__device__ __forceinline__ float b2f(unsigned short h) {
  return __uint_as_float(((unsigned)h) << 16);
}

// HW packed bf16 convert: dst.lo = bf16(a), dst.hi = bf16(b). One VALU op.
__device__ __forceinline__ unsigned cvtpk_bf16(float a, float b) {
  unsigned r;
  asm("v_cvt_pk_bf16_f32 %0, %1, %2" : "=v"(r) : "v"(a), "v"(b));
  return r;
}

// Staged layout (shorts) for matrix M[rows][512]:
//   off(row,k) = ((row>>4)*16 + (k>>5))*512 + (((k>>3)&3)*16 + (row&15))*8 + (k&7)
// = MFMA A/B fragment lane image; lane l of a wave reading chunk (rg,kt)
// gets SHORTS [l*8, l*8+8) = BYTES [l*16, l*16+16). Chunk = 1024 BYTES.
// Byte strides: ktile -> 1024 B; rowgroup (512-wide) -> 16*1024 B;
// rowgroup (1024-wide WT) -> 32*1024 B.
// ROUND-8 ROOT CAUSE (absmax 2750, rounds 6-8): enc_gemm's LDS shrank
// 64KB->32KB but kept alternate-buffer base 1<<15 (=32768) -> odd K-steps
// wrote/read PAST the LDS allocation. Fix: bases {0, 16384}.
__device__ __forceinline__ size_t staged_off(int row, int k) {
  return ((size_t)(row >> 4) * 16 + (k >> 5)) * 512 +
         (((k >> 3) & 3) * 16 + (row & 15)) * 8 + (k & 7);
}

// Same staged scheme for 1024-wide rows (WT matrices: [512 rows][1024 k]).
__device__ __forceinline__ size_t staged_off_w(int row, int k) {
  return ((size_t)(row >> 4) * 32 + (k >> 5)) * 512 +
         (((k >> 3) & 3) * 16 + (row & 15)) * 8 + (k & 7);
}

// XCD-affinity invariant (perf-only): the 256-row panel p of R/Rh16 is
// produced AND consumed by blocks with blockIdx%8 == p&7 in every kernel.

// ---------------------------------------------------------------------------
// Codebooks -> fp16, staged layout.
// ---------------------------------------------------------------------------
__global__ __launch_bounds__(256) void cbsplit_kernel(
    const float* __restrict__ cbs, unsigned short* __restrict__ Ch16) {
  int g = (blockIdx.x * 256 + threadIdx.x) * 4;  // flat over NL*KC*CB
  int k = g & (CB - 1);
  int lr = g >> 9;
  int layer = lr >> 10, row = lr & (KC - 1);
  float4 v = *(const float4*)(cbs + g);
  size_t off = (size_t)layer * (KC / 16) * 8192 + staged_off(row, k);
  *(ushort4*)(Ch16 + off) = make_ushort4(f2h(v.x), f2h(v.y), f2h(v.z), f2h(v.w));
}

// ---------------------------------------------------------------------------
// enc_W^T -> bf16 hi/lo split, staged layout. WTh/WTm are [512][1024] staged.
// ---------------------------------------------------------------------------
__global__ __launch_bounds__(256) void wsplit_kernel(
    const float* __restrict__ W, unsigned short* __restrict__ WTh,
    unsigned short* __restrict__ WTm) {
  int g = blockIdx.x * 256 + threadIdx.x;  // 131072 total
  int n = g >> 8;           // 0..511  (col of W = row of WT)
  int k0 = (g & 255) * 4;   // 0..1020 (row of W), 4-aligned -> same 8-chunk
  ushort4 h4, m4;
  unsigned short* hp = (unsigned short*)&h4;
  unsigned short* mp = (unsigned short*)&m4;
#pragma unroll
  for (int i = 0; i < 4; ++i) {
    float x = W[(size_t)(k0 + i) * CB + n];
    unsigned short h = f2b(x);
    hp[i] = h;
    mp[i] = f2b(x - b2f(h));
  }
  size_t off = staged_off_w(n, k0);
  *(ushort4*)(WTh + off) = h4;
  *(ushort4*)(WTm + off) = m4;
}

// ---------------------------------------------------------------------------
// cnorm[l*KC+k] = ||codebooks[l][k]||^2, fp64 (refine) + fp32 (stage1)
// ---------------------------------------------------------------------------
__global__ __launch_bounds__(256) void cnorm_kernel(
    const float* __restrict__ cbs, double* __restrict__ cnorm,
    float* __restrict__ cnormF) {
  int gw = (blockIdx.x * blockDim.x + threadIdx.x) >> 6;
  int lane = threadIdx.x & 63;
  if (gw >= NL * KC) return;
  const float* row = cbs + (size_t)gw * CB;
  double s = 0.0;
  for (int i = lane; i < CB; i += 64) {
    double v = (double)row[i];
    s += v * v;
  }
#pragma unroll
  for (int off = 32; off > 0; off >>= 1)
    s += __shfl_down(s, off, 64);
  if (lane == 0) { cnorm[gw] = s; cnormF[gw] = (float)s; }
}

// ---------------------------------------------------------------------------
// Encoder GEMM: R = X @ W + b via bf16 split (3 products: hh, mh, hm).
// B (WTh/WTm) direct-to-register (fragment layout => byte-identical to the
// gll+ds_read path). LDS: A only, double-buffered: 2 x 16KB, bases {0,16384}.
// ---------------------------------------------------------------------------
__global__ __launch_bounds__(256, 2) void enc_gemm(
    const float* __restrict__ X, const unsigned short* __restrict__ WTh,
    const unsigned short* __restrict__ WTm, const float* __restrict__ bias,
    float* __restrict__ R, unsigned short* __restrict__ Rh16) {
  __shared__ __align__(16) char lds[32768];  // [2] x (Ah 8K | Am 8K)
  int tid = threadIdx.x;
  int wave = tid >> 6, lane = tid & 63;
  int wm = wave >> 1, wn = wave & 1;
  int q = lane >> 4, l15 = lane & 15;
  // bits[0:2]=x(XCD), [3]=rb low bit, [4:5]=cbk, [6:8]=m
  int bx = blockIdx.x;
  int rb = ((bx & 7) << 1) + ((bx >> 3) & 1) + ((bx >> 6) << 4);
  int cbk = (bx >> 4) & 3;
  int row0 = rb * 128, n0 = cbk * 128;

  // A staging map: thread -> (local row ar, k-quarter aq)
  int ar = tid >> 1;          // 0..127
  int aq = (tid & 1) * 16;    // 0 or 16
  const float* xsrc = X + (size_t)(row0 + ar) * DIN + aq;
  int awoff = (ar >> 4) * 1024 + (((aq >> 3) & 3) * 16 + (ar & 15)) * 16;

  // B direct-load base (BYTES): colgroup (n0>>4)+wn*4, lane image at lane*16
  const char* bph = (const char*)WTh +
                    ((size_t)((n0 >> 4) + wn * 4) * 32) * 1024 + lane * 16;
  const char* bpm = (const char*)WTm +
                    ((size_t)((n0 >> 4) + wn * 4) * 32) * 1024 + lane * 16;

  f32x4 acc[4][4];
#pragma unroll
  for (int i = 0; i < 4; ++i)
#pragma unroll
    for (int j = 0; j < 4; ++j)
      acc[i][j] = (f32x4){0.f, 0.f, 0.f, 0.f};

  float xv[16];
  unsigned hp[8], mp[8];  // packed bf16 pairs
  uint4 BHa[4], BMa[4], BHb[4], BMb[4];  // B frags, 2-deep named buffers

#define LOADX(c)                                         \
  {                                                      \
    _Pragma("unroll") for (int j = 0; j < 4; ++j) {      \
      float4 v = *(const float4*)(xsrc + (c) * 32 + j * 4); \
      xv[4 * j + 0] = v.x; xv[4 * j + 1] = v.y;          \
      xv[4 * j + 2] = v.z; xv[4 * j + 3] = v.w;          \
    }                                                    \
  }
#define SPLITX()                                            \
  {                                                         \
    _Pragma("unroll") for (int j = 0; j < 8; ++j) {         \
      float x0 = xv[2 * j], x1 = xv[2 * j + 1];             \
      unsigned h = cvtpk_bf16(x0, x1);                      \
      float h0 = __uint_as_float(h << 16);                  \
      float h1 = __uint_as_float(h & 0xffff0000u);          \
      hp[j] = h;                                            \
      mp[j] = cvtpk_bf16(x0 - h0, x1 - h1);                 \
    }                                                       \
  }
#define WRITEA(bufbase)                                                     \
  {                                                                         \
    *(uint4*)(lds + (bufbase) + awoff) =                                    \
        make_uint4(hp[0], hp[1], hp[2], hp[3]);                             \
    *(uint4*)(lds + (bufbase) + awoff + 256) =                              \
        make_uint4(hp[4], hp[5], hp[6], hp[7]);                             \
    *(uint4*)(lds + (bufbase) + awoff + 8192) =                             \
        make_uint4(mp[0], mp[1], mp[2], mp[3]);                             \
    *(uint4*)(lds + (bufbase) + awoff + 8192 + 256) =                       \
        make_uint4(mp[4], mp[5], mp[6], mp[7]);                             \
  }
#define BLOADTO(ktile, BH, BM)                                              \
  {                                                                         \
    _Pragma("unroll") for (int tj = 0; tj < 4; ++tj) {                      \
      BH[tj] = *(const uint4*)(bph + (size_t)tj * 32768 + (size_t)(ktile) * 1024); \
      BM[tj] = *(const uint4*)(bpm + (size_t)tj * 32768 + (size_t)(ktile) * 1024); \
    }                                                                       \
  }
// One K-step: A from LDS buf CB_, B from regs BHc/BMc; prefetch next.
#define ESTEP(kt, CB_, NB_, BHc, BMc, BHn, BMn)                             \
  {                                                                         \
    if ((kt) < 31) {                                                        \
      WRITEA(NB_);                                                          \
      BLOADTO((kt) + 1, BHn, BMn);                                          \
    }                                                                       \
    if ((kt) < 30) LOADX((kt) + 2);                                         \
    const char* cb0 = lds + (CB_);                                          \
    bf16x8 ah[4], am[4];                                                    \
    _Pragma("unroll") for (int ti = 0; ti < 4; ++ti) {                      \
      ah[ti] = *(const bf16x8*)(cb0 + (wm * 4 + ti) * 1024 + lane * 16);    \
      am[ti] = *(const bf16x8*)(cb0 + 8192 + (wm * 4 + ti) * 1024 + lane * 16); \
    }                                                                       \
    _Pragma("unroll") for (int tj = 0; tj < 4; ++tj) {                      \
      bf16x8 bh = *(const bf16x8*)&BHc[tj];                                 \
      bf16x8 bm = *(const bf16x8*)&BMc[tj];                                 \
      _Pragma("unroll") for (int ti = 0; ti < 4; ++ti)                      \
        acc[ti][tj] = __builtin_amdgcn_mfma_f32_16x16x32_bf16(ah[ti], bh, acc[ti][tj], 0, 0, 0); \
      _Pragma("unroll") for (int ti = 0; ti < 4; ++ti)                      \
        acc[ti][tj] = __builtin_amdgcn_mfma_f32_16x16x32_bf16(am[ti], bh, acc[ti][tj], 0, 0, 0); \
      _Pragma("unroll") for (int ti = 0; ti < 4; ++ti)                      \
        acc[ti][tj] = __builtin_amdgcn_mfma_f32_16x16x32_bf16(ah[ti], bm, acc[ti][tj], 0, 0, 0); \
    }                                                                       \
    if ((kt) < 30) SPLITX();                                                \
    __syncthreads();                                                        \
  }

  // prologue: chunk 0 split -> buf0; B(0) -> regs a; chunk 1 split in regs
  LOADX(0); SPLITX();
  WRITEA(0);
  BLOADTO(0, BHa, BMa);
  LOADX(1); SPLITX();
  __syncthreads();  // buf0 A ready

  for (int kt2 = 0; kt2 < 16; ++kt2) {
    ESTEP(2 * kt2,     0,     16384, BHa, BMa, BHb, BMb);
    ESTEP(2 * kt2 + 1, 16384, 0,     BHb, BMb, BHa, BMa);
  }

  // Epilogue: verified 16x16 C/D mapping (col = l15, row = q*4 + r).
#pragma unroll
  for (int ti = 0; ti < 4; ++ti) {
#pragma unroll
    for (int tj = 0; tj < 4; ++tj) {
      int col = n0 + wn * 64 + tj * 16 + l15;
      float bv = bias[col];
#pragma unroll
      for (int r = 0; r < 4; ++r) {
        int row = row0 + wm * 64 + ti * 16 + q * 4 + r;
        float val = acc[ti][tj][r] + bv;
        R[(size_t)row * CB + col] = val;
        Rh16[staged_off(row, col)] = f2h(val);
      }
    }
  }
#undef LOADX
#undef SPLITX
#undef WRITEA
#undef BLOADTO
#undef ESTEP
}

// ---------------------------------------------------------------------------
// Stage 1: 1-term fp16 MFMA distance GEMM. 256x128 tile, wave owns
// 64 rows x 128 cols; u64-key top-2 in-wave.
// A (Rh16) direct-to-register (wave-private, zero cross-wave reuse).
// LDS: B only, double-buffered: 2 x 8KB, bases {0, 8192}.
// ---------------------------------------------------------------------------
__global__ __launch_bounds__(256, 2) void vq_stage1(
    const unsigned short* __restrict__ Rh16,
    const unsigned short* __restrict__ Ch16,
    const float* __restrict__ cnormF, float4* __restrict__ cand) {
  __shared__ __align__(16) char lds[16384];  // [2] x B 8KB
  int tid = threadIdx.x;
  int wave = tid >> 6, lane = tid & 63;
  int q = lane >> 4, l15 = lane & 15;
  int g = blockIdx.x;
  int rb = (g & 7) + ((g >> 6) << 3);  // 8 col-blocks of rb share an XCD
  int cbk = (g >> 3) & 7;
  int row0 = rb * 256, n0 = cbk * 128;

  f32x4 acc[4][8];
#pragma unroll
  for (int i = 0; i < 4; ++i)
#pragma unroll
    for (int j = 0; j < 8; ++j)
      acc[i][j] = (f32x4){0.f, 0.f, 0.f, 0.f};

  // A direct (BYTES): wave w owns rowgroups w*4..w*4+3; lane image at lane*16
  const char* aptr = (const char*)Rh16 +
                     ((size_t)(row0 >> 4) + wave * 4) * 16 * 1024 + lane * 16;
  // B staging: wave w stages colgroups w*2, w*2+1 (4-way read reuse)
  const unsigned short* gB =
      Ch16 + ((size_t)(n0 >> 4) + wave * 2) * 8192 + lane * 8;
  char* lB = lds + wave * 2 * 1024;

#define S1_ISSUEB(ktile, bufbase)                                            \
  {                                                                          \
    _Pragma("unroll") for (int s = 0; s < 2; ++s) {                          \
      __builtin_amdgcn_global_load_lds(                                      \
          (const __attribute__((address_space(1))) void*)(                   \
              gB + (size_t)s * 8192 + (ktile) * 512),                        \
          (__attribute__((address_space(3))) void*)(lB + (bufbase) + s * 1024), \
          16, 0, 0);                                                         \
    }                                                                        \
  }
#define ALOADTO(ktile, A)                                                    \
  {                                                                          \
    _Pragma("unroll") for (int ri = 0; ri < 4; ++ri)                         \
      A[ri] = *(const uint4*)(aptr + (size_t)ri * 16384 + (size_t)(ktile) * 1024); \
  }
#define S1STEP(kt, CURB, NXTB, Ac, An)                                       \
  {                                                                          \
    if ((kt) < 15) {                                                         \
      S1_ISSUEB((kt) + 1, NXTB);                                             \
      ALOADTO((kt) + 1, An);                                                 \
    }                                                                        \
    const char* cbp = lds + (CURB);                                          \
    _Pragma("unroll") for (int tj = 0; tj < 8; ++tj) {                       \
      half8 b = *(const half8*)(cbp + tj * 1024 + lane * 16);                \
      _Pragma("unroll") for (int ri = 0; ri < 4; ++ri)                       \
        acc[ri][tj] = __builtin_amdgcn_mfma_f32_16x16x32_f16(                \
            *(const half8*)&Ac[ri], b, acc[ri][tj], 0, 0, 0);                \
    }                                                                        \
    __syncthreads();                                                         \
  }

  uint4 Aa[4], Ab[4];  // A frags, 2-deep named buffers

  S1_ISSUEB(0, 0);
  ALOADTO(0, Aa);
  __syncthreads();  // buf0 B ready

  for (int kt2 = 0; kt2 < 8; ++kt2) {
    S1STEP(2 * kt2,     0,    8192, Aa, Ab);
    S1STEP(2 * kt2 + 1, 8192, 0,    Ab, Aa);
  }
#undef S1_ISSUEB
#undef ALOADTO
#undef S1STEP

  // Epilogue: d = cn - 2S; per-row top-2 over 128 cols, all in-wave.
  float cn[8]; int coln[8];
#pragma unroll
  for (int tj = 0; tj < 8; ++tj) {
    coln[tj] = n0 + tj * 16 + l15;
    cn[tj] = cnormF[coln[tj]];
  }
#pragma unroll
  for (int ri = 0; ri < 4; ++ri) {
#pragma unroll
    for (int r = 0; r < 4; ++r) {
      unsigned long long k1 = ~0ull, k2 = ~0ull;
#pragma unroll
      for (int tj = 0; tj < 8; ++tj) {
        float v = cn[tj] - 2.0f * acc[ri][tj][r];
        unsigned u = __float_as_uint(v);
        u = (u & 0x80000000u) ? ~u : (u | 0x80000000u);
        unsigned long long key =
            ((unsigned long long)u << 32) | (unsigned)coln[tj];
        if (key < k1) { k2 = k1; k1 = key; }
        else if (key < k2) { k2 = key; }
      }
#pragma unroll
      for (int mask = 1; mask <= 8; mask <<= 1) {
        unsigned long long o1 = __shfl_xor(k1, mask, 64);
        unsigned long long o2 = __shfl_xor(k2, mask, 64);
        if (o1 < k1) { k2 = (k1 < o2) ? k1 : o2; k1 = o1; }
        else { k2 = (k2 < o1) ? k2 : o1; }
      }
      if (l15 == 0) {
        unsigned s1 = (unsigned)(k1 >> 32), s2 = (unsigned)(k2 >> 32);
        unsigned b1 = (s1 & 0x80000000u) ? (s1 ^ 0x80000000u) : ~s1;
        unsigned b2 = (s2 & 0x80000000u) ? (s2 ^ 0x80000000u) : ~s2;
        int row = row0 + wave * 64 + ri * 16 + q * 4 + r;
        cand[(size_t)row * 8 + cbk] = make_float4(
            __uint_as_float(b1), __int_as_float((int)(unsigned)k1),
            __uint_as_float(b2), __int_as_float((int)(unsigned)k2));
      }
    }
  }
}

// ---------------------------------------------------------------------------
// Stage 2: combine 8 chunk top-2s; fp64-refine near-ties (vs fp32 R);
// write id; update residual (row-major R) + staged fp16 Rh16.
// Worklist-parallel refine; 32 rows/block; XCD-affinity block remap.
// ---------------------------------------------------------------------------
__global__ __launch_bounds__(256) void vq_refine(
    const float* __restrict__ cb, const double* __restrict__ cnorm,
    const float4* __restrict__ cand, float* __restrict__ R,
    unsigned short* __restrict__ Rh16, float* __restrict__ idsF, int layer) {
  __shared__ int sIdx[32][16];
  __shared__ int sCnt[32];
  __shared__ int sBest[32];
  __shared__ int sPair[512];
  __shared__ int sNP;
  __shared__ double sD[32][16];

  int tid = threadIdx.x;
  int b = blockIdx.x;
  // bits [0:2]->v[3:5] (panel), [3:5]->v[0:2], [6:8]->v[6:8]; XCD=b&7=(v>>3)&7
  int v = ((b & 7) << 3) + ((b >> 3) & 7) + ((b >> 6) << 6);
  int row0 = v * 32;

  if (tid == 0) sNP = 0;
  __syncthreads();

  if (tid < 32) {
    int row = row0 + tid;
    float vv[16]; int ix[16];
#pragma unroll
    for (int c = 0; c < 8; ++c) {
      float4 e = cand[(size_t)row * 8 + c];
      vv[2 * c] = e.x;     ix[2 * c] = __float_as_int(e.y);
      vv[2 * c + 1] = e.z; ix[2 * c + 1] = __float_as_int(e.w);
    }
    float M = FLT_MAX; int I = INT_MAX;
#pragma unroll
    for (int p = 0; p < 16; ++p)
      if (vv[p] < M || (vv[p] == M && ix[p] < I)) { M = vv[p]; I = ix[p]; }
    int cnt = 0;
#pragma unroll
    for (int p = 0; p < 16; ++p)
      if (vv[p] < M + DELTA && cnt < 16) sIdx[tid][cnt++] = ix[p];
    sCnt[tid] = cnt;
    sBest[tid] = I;
    if (cnt >= 2) {
      int base = atomicAdd(&sNP, cnt);
      for (int c = 0; c < cnt; ++c) sPair[base + c] = (tid << 4) | c;
    }
  }
  __syncthreads();

  int np = sNP;
  int wave = tid >> 6, lane = tid & 63;
  for (int p = wave; p < np; p += 4) {
    int pr = sPair[p];
    int r = pr >> 4, c = pr & 15;
    int idx = sIdx[r][c];
    const float* rrow = R + (size_t)(row0 + r) * CB;
    const float* crow = cb + (size_t)idx * CB;
    double s = 0.0;
#pragma unroll
    for (int e = 0; e < CB; e += 64)
      s += (double)rrow[e + lane] * (double)crow[e + lane];
#pragma unroll
    for (int off = 32; off > 0; off >>= 1)
      s += __shfl_xor(s, off, 64);
    if (lane == 0) sD[r][c] = cnorm[idx] - 2.0 * s;
  }
  __syncthreads();

  if (tid < 32) {
    int cnt = sCnt[tid];
    if (cnt >= 2) {
      double bestD = 1e300; int bestI = INT_MAX;
      for (int c = 0; c < cnt; ++c) {
        double d = sD[tid][c]; int idx = sIdx[tid][c];
        if (d < bestD || (d == bestD && idx < bestI)) { bestD = d; bestI = idx; }
      }
      sBest[tid] = bestI;
    }
    idsF[(size_t)(row0 + tid) * NL + layer] = (float)sBest[tid];
  }
  __syncthreads();

  // residual update: 4 elements per thread per iter
  for (int it = tid; it < 32 * (CB / 4); it += 256) {
    int r = it >> 7, dq = (it & 127) * 4;
    int row = row0 + r;
    size_t o = (size_t)row * CB + dq;
    float4 rv = *(const float4*)(R + o);
    const float* crow = cb + (size_t)sBest[r] * CB + dq;
    float nv[4] = {rv.x - crow[0], rv.y - crow[1], rv.z - crow[2], rv.w - crow[3]};
    *(float4*)(R + o) = make_float4(nv[0], nv[1], nv[2], nv[3]);
    size_t so = staged_off(row, dq);  // dq aligned 4 -> one chunk
    *(ushort4*)(Rh16 + so) =
        make_ushort4(f2h(nv[0]), f2h(nv[1]), f2h(nv[2]), f2h(nv[3]));
  }
}

// ---------------------------------------------------------------------------
// recon[b][j] = dec_b[j] + sum_l ids[b][l] * dec_W[l][j]
// ---------------------------------------------------------------------------
__global__ __launch_bounds__(256) void recon_kernel(
    const float* __restrict__ idsF, const float* __restrict__ decW,
    const float* __restrict__ decb, float* __restrict__ recon) {
  int g = blockIdx.x * 256 + threadIdx.x;
  int b = g >> 9, j = g & (CB - 1);
  float s = decb[j];
#pragma unroll
  for (int l = 0; l < NL; ++l)
    s += idsF[(size_t)b * NL + l] * decW[l * CB + j];
  recon[g] = s;
}

extern "C" void kernel_launch(void* const* d_in, const int* in_sizes, int n_in,
                              void* d_out, int out_size, void* d_ws, size_t ws_size,
                              hipStream_t stream) {
  const float* X    = (const float*)d_in[0];
  const float* encW = (const float*)d_in[1];
  const float* encb = (const float*)d_in[2];
  const float* cbs  = (const float*)d_in[3];
  const float* decW = (const float*)d_in[4];
  const float* decb = (const float*)d_in[5];

  float* out = (float*)d_out;
  float* recon = out;
  float* idsF = out + (size_t)BB * CB;

  char* ws = (char*)d_ws;
  float* R = (float*)ws;                     ws += (size_t)BB * CB * 4;        // 32 MB
  unsigned short* Rh16 = (unsigned short*)ws; ws += (size_t)BB * CB * 2;       // 16 MB
  unsigned short* Ch16 = (unsigned short*)ws; ws += (size_t)NL * KC * CB * 2;  // 4 MB
  double* cnorm = (double*)ws;               ws += (size_t)NL * KC * 8;        // 32 KB
  float* cnormF = (float*)ws;                ws += (size_t)NL * KC * 4;        // 16 KB
  float4* cand = (float4*)ws;                ws += (size_t)BB * 8 * 16;        // 2 MB
  unsigned short* WTh = (unsigned short*)ws; ws += (size_t)CB * DIN * 2;       // 1 MB
  unsigned short* WTm = (unsigned short*)ws;                                   // 1 MB

  cbsplit_kernel<<<(NL * KC * CB) / 1024, 256, 0, stream>>>(cbs, Ch16);
  cnorm_kernel<<<(NL * KC) / 4, 256, 0, stream>>>(cbs, cnorm, cnormF);
  wsplit_kernel<<<(CB * DIN / 4) / 256, 256, 0, stream>>>(encW, WTh, WTm);
  enc_gemm<<<(BB / 128) * (CB / 128), 256, 0, stream>>>(X, WTh, WTm, encb, R, Rh16);
  for (int l = 0; l < NL; ++l) {
    const float* cbl = cbs + (size_t)l * KC * CB;
    vq_stage1<<<(BB / 256) * 8, 256, 0, stream>>>(
        Rh16, Ch16 + (size_t)l * KC * CB, cnormF + (size_t)l * KC, cand);
    vq_refine<<<BB / 32, 256, 0, stream>>>(cbl, cnorm + (size_t)l * KC, cand,
                                           R, Rh16, idsF, l);
  }
  recon_kernel<<<(BB * CB) / 256, 256, 0, stream>>>(idsF, decW, decb, recon);
}

// Round 11
// 387.701 us; speedup vs baseline: 1.0004x; 1.0004x over previous
//
#include <hip/hip_runtime.h>
#include <float.h>
#include <limits.h>

// Problem constants
#define BB 16384   // batch rows
#define DIN 1024   // encoder input dim
#define CB 512     // codebook dim
#define KC 1024    // codewords per layer
#define NL 4       // layers

// Refine margin: fp16 1-term distance noise std ~0.022, max ~0.13.
// 0.25 = ~8 sigma AND >= 2x max single-value error (certainty bound).
#define DELTA 0.25f

typedef __attribute__((ext_vector_type(8))) _Float16 half8;
typedef __attribute__((ext_vector_type(8))) short bf16x8;
typedef __attribute__((ext_vector_type(4))) float f32x4;

__device__ __forceinline__ unsigned short f2h(float f) {
  _Float16 h = (_Float16)f;  // RTN
  return *(unsigned short*)&h;
}

// fp32 -> bf16 RTNE (wsplit only)
__device__ __forceinline__ unsigned short f2b(float f) {
  unsigned u = __float_as_uint(f);
  unsigned r = u + 0x7fffu + ((u >> 16) & 1u);
  return (unsigned short)(r >> 16);
}
__device__ __forceinline__ float b2f(unsigned short h) {
  return __uint_as_float(((unsigned)h) << 16);
}

// HW packed bf16 convert: dst.lo = bf16(a), dst.hi = bf16(b). One VALU op.
__device__ __forceinline__ unsigned cvtpk_bf16(float a, float b) {
  unsigned r;
  asm("v_cvt_pk_bf16_f32 %0, %1, %2" : "=v"(r) : "v"(a), "v"(b));
  return r;
}

// Staged layout (shorts) for matrix M[rows][512]:
//   off(row,k) = ((row>>4)*16 + (k>>5))*512 + (((k>>3)&3)*16 + (row&15))*8 + (k&7)
// = MFMA A/B fragment lane image; lane l of a wave reading chunk (rg,kt)
// gets SHORTS [l*8, l*8+8) = BYTES [l*16, l*16+16). Chunk = 1024 BYTES.
__device__ __forceinline__ size_t staged_off(int row, int k) {
  return ((size_t)(row >> 4) * 16 + (k >> 5)) * 512 +
         (((k >> 3) & 3) * 16 + (row & 15)) * 8 + (k & 7);
}

// Same staged scheme for 1024-wide rows (WT matrices: [512 rows][1024 k]).
__device__ __forceinline__ size_t staged_off_w(int row, int k) {
  return ((size_t)(row >> 4) * 32 + (k >> 5)) * 512 +
         (((k >> 3) & 3) * 16 + (row & 15)) * 8 + (k & 7);
}

// XCD-affinity invariant (perf-only): the 256-row panel p of R/Rh16 is
// produced AND consumed by blocks with blockIdx%8 == p&7 in every kernel.

// ---------------------------------------------------------------------------
// Codebooks -> fp16, staged layout.
// ---------------------------------------------------------------------------
__global__ __launch_bounds__(256) void cbsplit_kernel(
    const float* __restrict__ cbs, unsigned short* __restrict__ Ch16) {
  int g = (blockIdx.x * 256 + threadIdx.x) * 4;  // flat over NL*KC*CB
  int k = g & (CB - 1);
  int lr = g >> 9;
  int layer = lr >> 10, row = lr & (KC - 1);
  float4 v = *(const float4*)(cbs + g);
  size_t off = (size_t)layer * (KC / 16) * 8192 + staged_off(row, k);
  *(ushort4*)(Ch16 + off) = make_ushort4(f2h(v.x), f2h(v.y), f2h(v.z), f2h(v.w));
}

// ---------------------------------------------------------------------------
// enc_W^T -> bf16 hi/lo split, staged layout. WTh/WTm are [512][1024] staged.
// ---------------------------------------------------------------------------
__global__ __launch_bounds__(256) void wsplit_kernel(
    const float* __restrict__ W, unsigned short* __restrict__ WTh,
    unsigned short* __restrict__ WTm) {
  int g = blockIdx.x * 256 + threadIdx.x;  // 131072 total
  int n = g >> 8;           // 0..511  (col of W = row of WT)
  int k0 = (g & 255) * 4;   // 0..1020 (row of W), 4-aligned -> same 8-chunk
  ushort4 h4, m4;
  unsigned short* hp = (unsigned short*)&h4;
  unsigned short* mp = (unsigned short*)&m4;
#pragma unroll
  for (int i = 0; i < 4; ++i) {
    float x = W[(size_t)(k0 + i) * CB + n];
    unsigned short h = f2b(x);
    hp[i] = h;
    mp[i] = f2b(x - b2f(h));
  }
  size_t off = staged_off_w(n, k0);
  *(ushort4*)(WTh + off) = h4;
  *(ushort4*)(WTm + off) = m4;
}

// ---------------------------------------------------------------------------
// cnorm[l*KC+k] = ||codebooks[l][k]||^2, fp64 (refine) + fp32 (stage1)
// ---------------------------------------------------------------------------
__global__ __launch_bounds__(256) void cnorm_kernel(
    const float* __restrict__ cbs, double* __restrict__ cnorm,
    float* __restrict__ cnormF) {
  int gw = (blockIdx.x * blockDim.x + threadIdx.x) >> 6;
  int lane = threadIdx.x & 63;
  if (gw >= NL * KC) return;
  const float* row = cbs + (size_t)gw * CB;
  double s = 0.0;
  for (int i = lane; i < CB; i += 64) {
    double v = (double)row[i];
    s += v * v;
  }
#pragma unroll
  for (int off = 32; off > 0; off >>= 1)
    s += __shfl_down(s, off, 64);
  if (lane == 0) { cnorm[gw] = s; cnormF[gw] = (float)s; }
}

// ---------------------------------------------------------------------------
// Encoder GEMM: R = X @ W + b via bf16 split (3 products: hh, mh, hm).
// ROUND-9 PASSING FORM (verbatim): B (WTh/WTm) direct-to-register; A via
// LDS double-buffer 2x16KB bases {0,16384}; cvt_pk split; fused Rh16 write.
// ---------------------------------------------------------------------------
__global__ __launch_bounds__(256, 2) void enc_gemm(
    const float* __restrict__ X, const unsigned short* __restrict__ WTh,
    const unsigned short* __restrict__ WTm, const float* __restrict__ bias,
    float* __restrict__ R, unsigned short* __restrict__ Rh16) {
  __shared__ __align__(16) char lds[32768];  // [2] x (Ah 8K | Am 8K)
  int tid = threadIdx.x;
  int wave = tid >> 6, lane = tid & 63;
  int wm = wave >> 1, wn = wave & 1;
  int q = lane >> 4, l15 = lane & 15;
  // bits[0:2]=x(XCD), [3]=rb low bit, [4:5]=cbk, [6:8]=m
  int bx = blockIdx.x;
  int rb = ((bx & 7) << 1) + ((bx >> 3) & 1) + ((bx >> 6) << 4);
  int cbk = (bx >> 4) & 3;
  int row0 = rb * 128, n0 = cbk * 128;

  // A staging map: thread -> (local row ar, k-quarter aq)
  int ar = tid >> 1;          // 0..127
  int aq = (tid & 1) * 16;    // 0 or 16
  const float* xsrc = X + (size_t)(row0 + ar) * DIN + aq;
  int awoff = (ar >> 4) * 1024 + (((aq >> 3) & 3) * 16 + (ar & 15)) * 16;

  // B direct-load base (BYTES): colgroup (n0>>4)+wn*4, lane image at lane*16
  const char* bph = (const char*)WTh +
                    ((size_t)((n0 >> 4) + wn * 4) * 32) * 1024 + lane * 16;
  const char* bpm = (const char*)WTm +
                    ((size_t)((n0 >> 4) + wn * 4) * 32) * 1024 + lane * 16;

  f32x4 acc[4][4];
#pragma unroll
  for (int i = 0; i < 4; ++i)
#pragma unroll
    for (int j = 0; j < 4; ++j)
      acc[i][j] = (f32x4){0.f, 0.f, 0.f, 0.f};

  float xv[16];
  unsigned hp[8], mp[8];  // packed bf16 pairs
  uint4 BHa[4], BMa[4], BHb[4], BMb[4];  // B frags, 2-deep named buffers

#define LOADX(c)                                         \
  {                                                      \
    _Pragma("unroll") for (int j = 0; j < 4; ++j) {      \
      float4 v = *(const float4*)(xsrc + (c) * 32 + j * 4); \
      xv[4 * j + 0] = v.x; xv[4 * j + 1] = v.y;          \
      xv[4 * j + 2] = v.z; xv[4 * j + 3] = v.w;          \
    }                                                    \
  }
#define SPLITX()                                            \
  {                                                         \
    _Pragma("unroll") for (int j = 0; j < 8; ++j) {         \
      float x0 = xv[2 * j], x1 = xv[2 * j + 1];             \
      unsigned h = cvtpk_bf16(x0, x1);                      \
      float h0 = __uint_as_float(h << 16);                  \
      float h1 = __uint_as_float(h & 0xffff0000u);          \
      hp[j] = h;                                            \
      mp[j] = cvtpk_bf16(x0 - h0, x1 - h1);                 \
    }                                                       \
  }
#define WRITEA(bufbase)                                                     \
  {                                                                         \
    *(uint4*)(lds + (bufbase) + awoff) =                                    \
        make_uint4(hp[0], hp[1], hp[2], hp[3]);                             \
    *(uint4*)(lds + (bufbase) + awoff + 256) =                              \
        make_uint4(hp[4], hp[5], hp[6], hp[7]);                             \
    *(uint4*)(lds + (bufbase) + awoff + 8192) =                             \
        make_uint4(mp[0], mp[1], mp[2], mp[3]);                             \
    *(uint4*)(lds + (bufbase) + awoff + 8192 + 256) =                       \
        make_uint4(mp[4], mp[5], mp[6], mp[7]);                             \
  }
#define BLOADTO(ktile, BH, BM)                                              \
  {                                                                         \
    _Pragma("unroll") for (int tj = 0; tj < 4; ++tj) {                      \
      BH[tj] = *(const uint4*)(bph + (size_t)tj * 32768 + (size_t)(ktile) * 1024); \
      BM[tj] = *(const uint4*)(bpm + (size_t)tj * 32768 + (size_t)(ktile) * 1024); \
    }                                                                       \
  }
// One K-step: A from LDS buf CB_, B from regs BHc/BMc; prefetch next.
#define ESTEP(kt, CB_, NB_, BHc, BMc, BHn, BMn)                             \
  {                                                                         \
    if ((kt) < 31) {                                                        \
      WRITEA(NB_);                                                          \
      BLOADTO((kt) + 1, BHn, BMn);                                          \
    }                                                                       \
    if ((kt) < 30) LOADX((kt) + 2);                                         \
    const char* cb0 = lds + (CB_);                                          \
    bf16x8 ah[4], am[4];                                                    \
    _Pragma("unroll") for (int ti = 0; ti < 4; ++ti) {                      \
      ah[ti] = *(const bf16x8*)(cb0 + (wm * 4 + ti) * 1024 + lane * 16);    \
      am[ti] = *(const bf16x8*)(cb0 + 8192 + (wm * 4 + ti) * 1024 + lane * 16); \
    }                                                                       \
    _Pragma("unroll") for (int tj = 0; tj < 4; ++tj) {                      \
      bf16x8 bh = *(const bf16x8*)&BHc[tj];                                 \
      bf16x8 bm = *(const bf16x8*)&BMc[tj];                                 \
      _Pragma("unroll") for (int ti = 0; ti < 4; ++ti)                      \
        acc[ti][tj] = __builtin_amdgcn_mfma_f32_16x16x32_bf16(ah[ti], bh, acc[ti][tj], 0, 0, 0); \
      _Pragma("unroll") for (int ti = 0; ti < 4; ++ti)                      \
        acc[ti][tj] = __builtin_amdgcn_mfma_f32_16x16x32_bf16(am[ti], bh, acc[ti][tj], 0, 0, 0); \
      _Pragma("unroll") for (int ti = 0; ti < 4; ++ti)                      \
        acc[ti][tj] = __builtin_amdgcn_mfma_f32_16x16x32_bf16(ah[ti], bm, acc[ti][tj], 0, 0, 0); \
    }                                                                       \
    if ((kt) < 30) SPLITX();                                                \
    __syncthreads();                                                        \
  }

  // prologue: chunk 0 split -> buf0; B(0) -> regs a; chunk 1 split in regs
  LOADX(0); SPLITX();
  WRITEA(0);
  BLOADTO(0, BHa, BMa);
  LOADX(1); SPLITX();
  __syncthreads();  // buf0 A ready

  for (int kt2 = 0; kt2 < 16; ++kt2) {
    ESTEP(2 * kt2,     0,     16384, BHa, BMa, BHb, BMb);
    ESTEP(2 * kt2 + 1, 16384, 0,     BHb, BMb, BHa, BMa);
  }

  // Epilogue: verified 16x16 C/D mapping (col = l15, row = q*4 + r).
#pragma unroll
  for (int ti = 0; ti < 4; ++ti) {
#pragma unroll
    for (int tj = 0; tj < 4; ++tj) {
      int col = n0 + wn * 64 + tj * 16 + l15;
      float bv = bias[col];
#pragma unroll
      for (int r = 0; r < 4; ++r) {
        int row = row0 + wm * 64 + ti * 16 + q * 4 + r;
        float val = acc[ti][tj][r] + bv;
        R[(size_t)row * CB + col] = val;
        Rh16[staged_off(row, col)] = f2h(val);
      }
    }
  }
#undef LOADX
#undef SPLITX
#undef WRITEA
#undef BLOADTO
#undef ESTEP
}

// ---------------------------------------------------------------------------
// Stage 1: 1-term fp16 MFMA distance GEMM.
// ROUND-5 PASSING FORM (verbatim): 256x128 tile, wave owns 64x128; A+B both
// via global_load_lds, double-buffered 2x24KB; u64-key top-2 in-wave.
// (Round-9's direct-A variant measured +11us across layers -- reverted.)
// ---------------------------------------------------------------------------
__global__ __launch_bounds__(256, 2) void vq_stage1(
    const unsigned short* __restrict__ Rh16,
    const unsigned short* __restrict__ Ch16,
    const float* __restrict__ cnormF, float4* __restrict__ cand) {
  __shared__ __align__(16) char lds[49152];  // [2] x (A 16KB | B 8KB)
  int tid = threadIdx.x;
  int wave = tid >> 6, lane = tid & 63;
  int q = lane >> 4, l15 = lane & 15;
  int g = blockIdx.x;
  int rb = (g & 7) + ((g >> 6) << 3);  // 8 col-blocks of rb share an XCD
  int cbk = (g >> 3) & 7;
  int row0 = rb * 256, n0 = cbk * 128;

  f32x4 acc[4][8];
#pragma unroll
  for (int i = 0; i < 4; ++i)
#pragma unroll
    for (int j = 0; j < 8; ++j)
      acc[i][j] = (f32x4){0.f, 0.f, 0.f, 0.f};

  // staging: wave w stages A rowgroups w*4..w*4+3 and B colgroups w*2,w*2+1
  const unsigned short* gA =
      Rh16 + ((size_t)(row0 >> 4) + wave * 4) * 8192 + lane * 8;
  const unsigned short* gB =
      Ch16 + ((size_t)(n0 >> 4) + wave * 2) * 8192 + lane * 8;
  char* lA = lds + wave * 4 * 1024;
  char* lB = lds + 16384 + wave * 2 * 1024;

#define STAGE1_ISSUE(ktile, bufbase)                                         \
  {                                                                          \
    _Pragma("unroll") for (int s = 0; s < 4; ++s) {                          \
      __builtin_amdgcn_global_load_lds(                                      \
          (const __attribute__((address_space(1))) void*)(                   \
              gA + (size_t)s * 8192 + (ktile) * 512),                        \
          (__attribute__((address_space(3))) void*)(lA + (bufbase) + s * 1024), \
          16, 0, 0);                                                         \
    }                                                                        \
    _Pragma("unroll") for (int s = 0; s < 2; ++s) {                          \
      __builtin_amdgcn_global_load_lds(                                      \
          (const __attribute__((address_space(1))) void*)(                   \
              gB + (size_t)s * 8192 + (ktile) * 512),                        \
          (__attribute__((address_space(3))) void*)(lB + (bufbase) + s * 1024), \
          16, 0, 0);                                                         \
    }                                                                        \
  }

  STAGE1_ISSUE(0, 0);
  __syncthreads();  // buf0 ready

  for (int kt = 0; kt < 16; ++kt) {
    int cur = kt & 1;
    if (kt < 15) STAGE1_ISSUE(kt + 1, (cur ^ 1) * 24576);
    const char* ca = lds + cur * 24576;
    const char* cbp = ca + 16384;
    half8 af[4];
#pragma unroll
    for (int ri = 0; ri < 4; ++ri)
      af[ri] = *(const half8*)(ca + (wave * 4 + ri) * 1024 + lane * 16);
#pragma unroll
    for (int tj = 0; tj < 8; ++tj) {
      half8 b = *(const half8*)(cbp + tj * 1024 + lane * 16);
#pragma unroll
      for (int ri = 0; ri < 4; ++ri)
        acc[ri][tj] = __builtin_amdgcn_mfma_f32_16x16x32_f16(af[ri], b, acc[ri][tj], 0, 0, 0);
    }
    __syncthreads();  // next buffer landed + all reads of cur done
  }
#undef STAGE1_ISSUE

  // Epilogue: d = cn - 2S; per-row top-2 over 128 cols, all in-wave.
  float cn[8]; int coln[8];
#pragma unroll
  for (int tj = 0; tj < 8; ++tj) {
    coln[tj] = n0 + tj * 16 + l15;
    cn[tj] = cnormF[coln[tj]];
  }
#pragma unroll
  for (int ri = 0; ri < 4; ++ri) {
#pragma unroll
    for (int r = 0; r < 4; ++r) {
      unsigned long long k1 = ~0ull, k2 = ~0ull;
#pragma unroll
      for (int tj = 0; tj < 8; ++tj) {
        float v = cn[tj] - 2.0f * acc[ri][tj][r];
        unsigned u = __float_as_uint(v);
        u = (u & 0x80000000u) ? ~u : (u | 0x80000000u);
        unsigned long long key =
            ((unsigned long long)u << 32) | (unsigned)coln[tj];
        if (key < k1) { k2 = k1; k1 = key; }
        else if (key < k2) { k2 = key; }
      }
#pragma unroll
      for (int mask = 1; mask <= 8; mask <<= 1) {
        unsigned long long o1 = __shfl_xor(k1, mask, 64);
        unsigned long long o2 = __shfl_xor(k2, mask, 64);
        if (o1 < k1) { k2 = (k1 < o2) ? k1 : o2; k1 = o1; }
        else { k2 = (k2 < o1) ? k2 : o1; }
      }
      if (l15 == 0) {
        unsigned s1 = (unsigned)(k1 >> 32), s2 = (unsigned)(k2 >> 32);
        unsigned b1 = (s1 & 0x80000000u) ? (s1 ^ 0x80000000u) : ~s1;
        unsigned b2 = (s2 & 0x80000000u) ? (s2 ^ 0x80000000u) : ~s2;
        int row = row0 + wave * 64 + ri * 16 + q * 4 + r;
        cand[(size_t)row * 8 + cbk] = make_float4(
            __uint_as_float(b1), __int_as_float((int)(unsigned)k1),
            __uint_as_float(b2), __int_as_float((int)(unsigned)k2));
      }
    }
  }
}

// ---------------------------------------------------------------------------
// Stage 2: combine 8 chunk top-2s; fp64-refine near-ties (vs fp32 R);
// write id; update residual (row-major R) + staged fp16 Rh16.
// Worklist-parallel refine; 32 rows/block; XCD-affinity block remap.
// ---------------------------------------------------------------------------
__global__ __launch_bounds__(256) void vq_refine(
    const float* __restrict__ cb, const double* __restrict__ cnorm,
    const float4* __restrict__ cand, float* __restrict__ R,
    unsigned short* __restrict__ Rh16, float* __restrict__ idsF, int layer) {
  __shared__ int sIdx[32][16];
  __shared__ int sCnt[32];
  __shared__ int sBest[32];
  __shared__ int sPair[512];
  __shared__ int sNP;
  __shared__ double sD[32][16];

  int tid = threadIdx.x;
  int b = blockIdx.x;
  // bits [0:2]->v[3:5] (panel), [3:5]->v[0:2], [6:8]->v[6:8]; XCD=b&7=(v>>3)&7
  int v = ((b & 7) << 3) + ((b >> 3) & 7) + ((b >> 6) << 6);
  int row0 = v * 32;

  if (tid == 0) sNP = 0;
  __syncthreads();

  if (tid < 32) {
    int row = row0 + tid;
    float vv[16]; int ix[16];
#pragma unroll
    for (int c = 0; c < 8; ++c) {
      float4 e = cand[(size_t)row * 8 + c];
      vv[2 * c] = e.x;     ix[2 * c] = __float_as_int(e.y);
      vv[2 * c + 1] = e.z; ix[2 * c + 1] = __float_as_int(e.w);
    }
    float M = FLT_MAX; int I = INT_MAX;
#pragma unroll
    for (int p = 0; p < 16; ++p)
      if (vv[p] < M || (vv[p] == M && ix[p] < I)) { M = vv[p]; I = ix[p]; }
    int cnt = 0;
#pragma unroll
    for (int p = 0; p < 16; ++p)
      if (vv[p] < M + DELTA && cnt < 16) sIdx[tid][cnt++] = ix[p];
    sCnt[tid] = cnt;
    sBest[tid] = I;
    if (cnt >= 2) {
      int base = atomicAdd(&sNP, cnt);
      for (int c = 0; c < cnt; ++c) sPair[base + c] = (tid << 4) | c;
    }
  }
  __syncthreads();

  int np = sNP;
  int wave = tid >> 6, lane = tid & 63;
  for (int p = wave; p < np; p += 4) {
    int pr = sPair[p];
    int r = pr >> 4, c = pr & 15;
    int idx = sIdx[r][c];
    const float* rrow = R + (size_t)(row0 + r) * CB;
    const float* crow = cb + (size_t)idx * CB;
    double s = 0.0;
#pragma unroll
    for (int e = 0; e < CB; e += 64)
      s += (double)rrow[e + lane] * (double)crow[e + lane];
#pragma unroll
    for (int off = 32; off > 0; off >>= 1)
      s += __shfl_xor(s, off, 64);
    if (lane == 0) sD[r][c] = cnorm[idx] - 2.0 * s;
  }
  __syncthreads();

  if (tid < 32) {
    int cnt = sCnt[tid];
    if (cnt >= 2) {
      double bestD = 1e300; int bestI = INT_MAX;
      for (int c = 0; c < cnt; ++c) {
        double d = sD[tid][c]; int idx = sIdx[tid][c];
        if (d < bestD || (d == bestD && idx < bestI)) { bestD = d; bestI = idx; }
      }
      sBest[tid] = bestI;
    }
    idsF[(size_t)(row0 + tid) * NL + layer] = (float)sBest[tid];
  }
  __syncthreads();

  // residual update: 4 elements per thread per iter
  for (int it = tid; it < 32 * (CB / 4); it += 256) {
    int r = it >> 7, dq = (it & 127) * 4;
    int row = row0 + r;
    size_t o = (size_t)row * CB + dq;
    float4 rv = *(const float4*)(R + o);
    const float* crow = cb + (size_t)sBest[r] * CB + dq;
    float nv[4] = {rv.x - crow[0], rv.y - crow[1], rv.z - crow[2], rv.w - crow[3]};
    *(float4*)(R + o) = make_float4(nv[0], nv[1], nv[2], nv[3]);
    size_t so = staged_off(row, dq);  // dq aligned 4 -> one chunk
    *(ushort4*)(Rh16 + so) =
        make_ushort4(f2h(nv[0]), f2h(nv[1]), f2h(nv[2]), f2h(nv[3]));
  }
}

// ---------------------------------------------------------------------------
// recon[b][j] = dec_b[j] + sum_l ids[b][l] * dec_W[l][j]
// ---------------------------------------------------------------------------
__global__ __launch_bounds__(256) void recon_kernel(
    const float* __restrict__ idsF, const float* __restrict__ decW,
    const float* __restrict__ decb, float* __restrict__ recon) {
  int g = blockIdx.x * 256 + threadIdx.x;
  int b = g >> 9, j = g & (CB - 1);
  float s = decb[j];
#pragma unroll
  for (int l = 0; l < NL; ++l)
    s += idsF[(size_t)b * NL + l] * decW[l * CB + j];
  recon[g] = s;
}

extern "C" void kernel_launch(void* const* d_in, const int* in_sizes, int n_in,
                              void* d_out, int out_size, void* d_ws, size_t ws_size,
                              hipStream_t stream) {
  const float* X    = (const float*)d_in[0];
  const float* encW = (const float*)d_in[1];
  const float* encb = (const float*)d_in[2];
  const float* cbs  = (const float*)d_in[3];
  const float* decW = (const float*)d_in[4];
  const float* decb = (const float*)d_in[5];

  float* out = (float*)d_out;
  float* recon = out;
  float* idsF = out + (size_t)BB * CB;

  char* ws = (char*)d_ws;
  float* R = (float*)ws;                     ws += (size_t)BB * CB * 4;        // 32 MB
  unsigned short* Rh16 = (unsigned short*)ws; ws += (size_t)BB * CB * 2;       // 16 MB
  unsigned short* Ch16 = (unsigned short*)ws; ws += (size_t)NL * KC * CB * 2;  // 4 MB
  double* cnorm = (double*)ws;               ws += (size_t)NL * KC * 8;        // 32 KB
  float* cnormF = (float*)ws;                ws += (size_t)NL * KC * 4;        // 16 KB
  float4* cand = (float4*)ws;                ws += (size_t)BB * 8 * 16;        // 2 MB
  unsigned short* WTh = (unsigned short*)ws; ws += (size_t)CB * DIN * 2;       // 1 MB
  unsigned short* WTm = (unsigned short*)ws;                                   // 1 MB

  cbsplit_kernel<<<(NL * KC * CB) / 1024, 256, 0, stream>>>(cbs, Ch16);
  cnorm_kernel<<<(NL * KC) / 4, 256, 0, stream>>>(cbs, cnorm, cnormF);
  wsplit_kernel<<<(CB * DIN / 4) / 256, 256, 0, stream>>>(encW, WTh, WTm);
  enc_gemm<<<(BB / 128) * (CB / 128), 256, 0, stream>>>(X, WTh, WTm, encb, R, Rh16);
  for (int l = 0; l < NL; ++l) {
    const float* cbl = cbs + (size_t)l * KC * CB;
    vq_stage1<<<(BB / 256) * 8, 256, 0, stream>>>(
        Rh16, Ch16 + (size_t)l * KC * CB, cnormF + (size_t)l * KC, cand);
    vq_refine<<<BB / 32, 256, 0, stream>>>(cbl, cnorm + (size_t)l * KC, cand,
                                           R, Rh16, idsF, l);
  }
  recon_kernel<<<(BB * CB) / 256, 256, 0, stream>>>(idsF, decW, decb, recon);
}

// Round 12
// 358.086 us; speedup vs baseline: 1.0831x; 1.0827x over previous
//
#include <hip/hip_runtime.h>
#include <float.h>
#include <limits.h>

// Problem constants
#define BB 16384   // batch rows
#define DIN 1024   // encoder input dim
#define CB 512     // codebook dim
#define KC 1024    // codewords per layer
#define NL 4       // layers

// Refine margin: fp16 1-term distance noise std ~0.022, max ~0.13.
// 0.25 = ~8 sigma AND >= 2x max single-value error (certainty bound).
#define DELTA 0.25f

typedef __attribute__((ext_vector_type(8))) _Float16 half8;
typedef __attribute__((ext_vector_type(8))) short bf16x8;
typedef __attribute__((ext_vector_type(4))) float f32x4;

__device__ __forceinline__ unsigned short f2h(float f) {
  _Float16 h = (_Float16)f;  // RTN
  return *(unsigned short*)&h;
}

// fp32 -> bf16 RTNE (wsplit only)
__device__ __forceinline__ unsigned short f2b(float f) {
  unsigned u = __float_as_uint(f);
  unsigned r = u + 0x7fffu + ((u >> 16) & 1u);
  return (unsigned short)(r >> 16);
}
__device__ __forceinline__ float b2f(unsigned short h) {
  return __uint_as_float(((unsigned)h) << 16);
}

// HW packed bf16 convert: dst.lo = bf16(a), dst.hi = bf16(b). One VALU op.
__device__ __forceinline__ unsigned cvtpk_bf16(float a, float b) {
  unsigned r;
  asm("v_cvt_pk_bf16_f32 %0, %1, %2" : "=v"(r) : "v"(a), "v"(b));
  return r;
}

// Staged layout (shorts) for matrix M[rows][512]:
//   off(row,k) = ((row>>4)*16 + (k>>5))*512 + (((k>>3)&3)*16 + (row&15))*8 + (k&7)
// = MFMA A/B fragment lane image; lane l of a wave reading chunk (rg,kt)
// gets SHORTS [l*8, l*8+8) = BYTES [l*16, l*16+16). Chunk = 1024 BYTES.
__device__ __forceinline__ size_t staged_off(int row, int k) {
  return ((size_t)(row >> 4) * 16 + (k >> 5)) * 512 +
         (((k >> 3) & 3) * 16 + (row & 15)) * 8 + (k & 7);
}

// Same staged scheme for 1024-wide rows (WT matrices: [512 rows][1024 k]).
__device__ __forceinline__ size_t staged_off_w(int row, int k) {
  return ((size_t)(row >> 4) * 32 + (k >> 5)) * 512 +
         (((k >> 3) & 3) * 16 + (row & 15)) * 8 + (k & 7);
}

// XCD-affinity invariant (perf-only): the 256-row panel p of R/Rh16 is
// produced AND consumed by blocks with blockIdx%8 == p&7 in every kernel.

// ---------------------------------------------------------------------------
// Codebooks -> fp16, staged layout.
// ---------------------------------------------------------------------------
__global__ __launch_bounds__(256) void cbsplit_kernel(
    const float* __restrict__ cbs, unsigned short* __restrict__ Ch16) {
  int g = (blockIdx.x * 256 + threadIdx.x) * 4;  // flat over NL*KC*CB
  int k = g & (CB - 1);
  int lr = g >> 9;
  int layer = lr >> 10, row = lr & (KC - 1);
  float4 v = *(const float4*)(cbs + g);
  size_t off = (size_t)layer * (KC / 16) * 8192 + staged_off(row, k);
  *(ushort4*)(Ch16 + off) = make_ushort4(f2h(v.x), f2h(v.y), f2h(v.z), f2h(v.w));
}

// ---------------------------------------------------------------------------
// enc_W^T -> bf16 hi/lo split, staged layout. WTh/WTm are [512][1024] staged.
// ---------------------------------------------------------------------------
__global__ __launch_bounds__(256) void wsplit_kernel(
    const float* __restrict__ W, unsigned short* __restrict__ WTh,
    unsigned short* __restrict__ WTm) {
  int g = blockIdx.x * 256 + threadIdx.x;  // 131072 total
  int n = g >> 8;           // 0..511  (col of W = row of WT)
  int k0 = (g & 255) * 4;   // 0..1020 (row of W), 4-aligned -> same 8-chunk
  ushort4 h4, m4;
  unsigned short* hp = (unsigned short*)&h4;
  unsigned short* mp = (unsigned short*)&m4;
#pragma unroll
  for (int i = 0; i < 4; ++i) {
    float x = W[(size_t)(k0 + i) * CB + n];
    unsigned short h = f2b(x);
    hp[i] = h;
    mp[i] = f2b(x - b2f(h));
  }
  size_t off = staged_off_w(n, k0);
  *(ushort4*)(WTh + off) = h4;
  *(ushort4*)(WTm + off) = m4;
}

// ---------------------------------------------------------------------------
// cnorm[l*KC+k] = ||codebooks[l][k]||^2, fp64 (refine) + fp32 (stage1)
// ---------------------------------------------------------------------------
__global__ __launch_bounds__(256) void cnorm_kernel(
    const float* __restrict__ cbs, double* __restrict__ cnorm,
    float* __restrict__ cnormF) {
  int gw = (blockIdx.x * blockDim.x + threadIdx.x) >> 6;
  int lane = threadIdx.x & 63;
  if (gw >= NL * KC) return;
  const float* row = cbs + (size_t)gw * CB;
  double s = 0.0;
  for (int i = lane; i < CB; i += 64) {
    double v = (double)row[i];
    s += v * v;
  }
#pragma unroll
  for (int off = 32; off > 0; off >>= 1)
    s += __shfl_down(s, off, 64);
  if (lane == 0) { cnorm[gw] = s; cnormF[gw] = (float)s; }
}

// ---------------------------------------------------------------------------
// Encoder GEMM: R = X @ W + b via bf16 split (3 products: hh, mh, hm).
// ROUND-9 PASSING FORM (verbatim): B (WTh/WTm) direct-to-register; A via
// LDS double-buffer 2x16KB bases {0,16384}; cvt_pk split; fused Rh16 write.
// ---------------------------------------------------------------------------
__global__ __launch_bounds__(256, 2) void enc_gemm(
    const float* __restrict__ X, const unsigned short* __restrict__ WTh,
    const unsigned short* __restrict__ WTm, const float* __restrict__ bias,
    float* __restrict__ R, unsigned short* __restrict__ Rh16) {
  __shared__ __align__(16) char lds[32768];  // [2] x (Ah 8K | Am 8K)
  int tid = threadIdx.x;
  int wave = tid >> 6, lane = tid & 63;
  int wm = wave >> 1, wn = wave & 1;
  int q = lane >> 4, l15 = lane & 15;
  // bits[0:2]=x(XCD), [3]=rb low bit, [4:5]=cbk, [6:8]=m
  int bx = blockIdx.x;
  int rb = ((bx & 7) << 1) + ((bx >> 3) & 1) + ((bx >> 6) << 4);
  int cbk = (bx >> 4) & 3;
  int row0 = rb * 128, n0 = cbk * 128;

  // A staging map: thread -> (local row ar, k-quarter aq)
  int ar = tid >> 1;          // 0..127
  int aq = (tid & 1) * 16;    // 0 or 16
  const float* xsrc = X + (size_t)(row0 + ar) * DIN + aq;
  int awoff = (ar >> 4) * 1024 + (((aq >> 3) & 3) * 16 + (ar & 15)) * 16;

  // B direct-load base (BYTES): colgroup (n0>>4)+wn*4, lane image at lane*16
  const char* bph = (const char*)WTh +
                    ((size_t)((n0 >> 4) + wn * 4) * 32) * 1024 + lane * 16;
  const char* bpm = (const char*)WTm +
                    ((size_t)((n0 >> 4) + wn * 4) * 32) * 1024 + lane * 16;

  f32x4 acc[4][4];
#pragma unroll
  for (int i = 0; i < 4; ++i)
#pragma unroll
    for (int j = 0; j < 4; ++j)
      acc[i][j] = (f32x4){0.f, 0.f, 0.f, 0.f};

  float xv[16];
  unsigned hp[8], mp[8];  // packed bf16 pairs
  uint4 BHa[4], BMa[4], BHb[4], BMb[4];  // B frags, 2-deep named buffers

#define LOADX(c)                                         \
  {                                                      \
    _Pragma("unroll") for (int j = 0; j < 4; ++j) {      \
      float4 v = *(const float4*)(xsrc + (c) * 32 + j * 4); \
      xv[4 * j + 0] = v.x; xv[4 * j + 1] = v.y;          \
      xv[4 * j + 2] = v.z; xv[4 * j + 3] = v.w;          \
    }                                                    \
  }
#define SPLITX()                                            \
  {                                                         \
    _Pragma("unroll") for (int j = 0; j < 8; ++j) {         \
      float x0 = xv[2 * j], x1 = xv[2 * j + 1];             \
      unsigned h = cvtpk_bf16(x0, x1);                      \
      float h0 = __uint_as_float(h << 16);                  \
      float h1 = __uint_as_float(h & 0xffff0000u);          \
      hp[j] = h;                                            \
      mp[j] = cvtpk_bf16(x0 - h0, x1 - h1);                 \
    }                                                       \
  }
#define WRITEA(bufbase)                                                     \
  {                                                                         \
    *(uint4*)(lds + (bufbase) + awoff) =                                    \
        make_uint4(hp[0], hp[1], hp[2], hp[3]);                             \
    *(uint4*)(lds + (bufbase) + awoff + 256) =                              \
        make_uint4(hp[4], hp[5], hp[6], hp[7]);                             \
    *(uint4*)(lds + (bufbase) + awoff + 8192) =                             \
        make_uint4(mp[0], mp[1], mp[2], mp[3]);                             \
    *(uint4*)(lds + (bufbase) + awoff + 8192 + 256) =                       \
        make_uint4(mp[4], mp[5], mp[6], mp[7]);                             \
  }
#define BLOADTO(ktile, BH, BM)                                              \
  {                                                                         \
    _Pragma("unroll") for (int tj = 0; tj < 4; ++tj) {                      \
      BH[tj] = *(const uint4*)(bph + (size_t)tj * 32768 + (size_t)(ktile) * 1024); \
      BM[tj] = *(const uint4*)(bpm + (size_t)tj * 32768 + (size_t)(ktile) * 1024); \
    }                                                                       \
  }
// One K-step: A from LDS buf CB_, B from regs BHc/BMc; prefetch next.
#define ESTEP(kt, CB_, NB_, BHc, BMc, BHn, BMn)                             \
  {                                                                         \
    if ((kt) < 31) {                                                        \
      WRITEA(NB_);                                                          \
      BLOADTO((kt) + 1, BHn, BMn);                                          \
    }                                                                       \
    if ((kt) < 30) LOADX((kt) + 2);                                         \
    const char* cb0 = lds + (CB_);                                          \
    bf16x8 ah[4], am[4];                                                    \
    _Pragma("unroll") for (int ti = 0; ti < 4; ++ti) {                      \
      ah[ti] = *(const bf16x8*)(cb0 + (wm * 4 + ti) * 1024 + lane * 16);    \
      am[ti] = *(const bf16x8*)(cb0 + 8192 + (wm * 4 + ti) * 1024 + lane * 16); \
    }                                                                       \
    _Pragma("unroll") for (int tj = 0; tj < 4; ++tj) {                      \
      bf16x8 bh = *(const bf16x8*)&BHc[tj];                                 \
      bf16x8 bm = *(const bf16x8*)&BMc[tj];                                 \
      _Pragma("unroll") for (int ti = 0; ti < 4; ++ti)                      \
        acc[ti][tj] = __builtin_amdgcn_mfma_f32_16x16x32_bf16(ah[ti], bh, acc[ti][tj], 0, 0, 0); \
      _Pragma("unroll") for (int ti = 0; ti < 4; ++ti)                      \
        acc[ti][tj] = __builtin_amdgcn_mfma_f32_16x16x32_bf16(am[ti], bh, acc[ti][tj], 0, 0, 0); \
      _Pragma("unroll") for (int ti = 0; ti < 4; ++ti)                      \
        acc[ti][tj] = __builtin_amdgcn_mfma_f32_16x16x32_bf16(ah[ti], bm, acc[ti][tj], 0, 0, 0); \
    }                                                                       \
    if ((kt) < 30) SPLITX();                                                \
    __syncthreads();                                                        \
  }

  // prologue: chunk 0 split -> buf0; B(0) -> regs a; chunk 1 split in regs
  LOADX(0); SPLITX();
  WRITEA(0);
  BLOADTO(0, BHa, BMa);
  LOADX(1); SPLITX();
  __syncthreads();  // buf0 A ready

  for (int kt2 = 0; kt2 < 16; ++kt2) {
    ESTEP(2 * kt2,     0,     16384, BHa, BMa, BHb, BMb);
    ESTEP(2 * kt2 + 1, 16384, 0,     BHb, BMb, BHa, BMa);
  }

  // Epilogue: verified 16x16 C/D mapping (col = l15, row = q*4 + r).
#pragma unroll
  for (int ti = 0; ti < 4; ++ti) {
#pragma unroll
    for (int tj = 0; tj < 4; ++tj) {
      int col = n0 + wn * 64 + tj * 16 + l15;
      float bv = bias[col];
#pragma unroll
      for (int r = 0; r < 4; ++r) {
        int row = row0 + wm * 64 + ti * 16 + q * 4 + r;
        float val = acc[ti][tj][r] + bv;
        R[(size_t)row * CB + col] = val;
        Rh16[staged_off(row, col)] = f2h(val);
      }
    }
  }
#undef LOADX
#undef SPLITX
#undef WRITEA
#undef BLOADTO
#undef ESTEP
}

// ---------------------------------------------------------------------------
// Stage 1: 1-term fp16 MFMA distance GEMM.
// ROUND-5/11 PASSING FORM (verbatim): 256x128 tile, wave owns 64x128; A+B
// via global_load_lds, double-buffered 2x24KB; u64-key top-2 in-wave.
// ---------------------------------------------------------------------------
__global__ __launch_bounds__(256, 2) void vq_stage1(
    const unsigned short* __restrict__ Rh16,
    const unsigned short* __restrict__ Ch16,
    const float* __restrict__ cnormF, float4* __restrict__ cand) {
  __shared__ __align__(16) char lds[49152];  // [2] x (A 16KB | B 8KB)
  int tid = threadIdx.x;
  int wave = tid >> 6, lane = tid & 63;
  int q = lane >> 4, l15 = lane & 15;
  int g = blockIdx.x;
  int rb = (g & 7) + ((g >> 6) << 3);  // 8 col-blocks of rb share an XCD
  int cbk = (g >> 3) & 7;
  int row0 = rb * 256, n0 = cbk * 128;

  f32x4 acc[4][8];
#pragma unroll
  for (int i = 0; i < 4; ++i)
#pragma unroll
    for (int j = 0; j < 8; ++j)
      acc[i][j] = (f32x4){0.f, 0.f, 0.f, 0.f};

  // staging: wave w stages A rowgroups w*4..w*4+3 and B colgroups w*2,w*2+1
  const unsigned short* gA =
      Rh16 + ((size_t)(row0 >> 4) + wave * 4) * 8192 + lane * 8;
  const unsigned short* gB =
      Ch16 + ((size_t)(n0 >> 4) + wave * 2) * 8192 + lane * 8;
  char* lA = lds + wave * 4 * 1024;
  char* lB = lds + 16384 + wave * 2 * 1024;

#define STAGE1_ISSUE(ktile, bufbase)                                         \
  {                                                                          \
    _Pragma("unroll") for (int s = 0; s < 4; ++s) {                          \
      __builtin_amdgcn_global_load_lds(                                      \
          (const __attribute__((address_space(1))) void*)(                   \
              gA + (size_t)s * 8192 + (ktile) * 512),                        \
          (__attribute__((address_space(3))) void*)(lA + (bufbase) + s * 1024), \
          16, 0, 0);                                                         \
    }                                                                        \
    _Pragma("unroll") for (int s = 0; s < 2; ++s) {                          \
      __builtin_amdgcn_global_load_lds(                                      \
          (const __attribute__((address_space(1))) void*)(                   \
              gB + (size_t)s * 8192 + (ktile) * 512),                        \
          (__attribute__((address_space(3))) void*)(lB + (bufbase) + s * 1024), \
          16, 0, 0);                                                         \
    }                                                                        \
  }

  STAGE1_ISSUE(0, 0);
  __syncthreads();  // buf0 ready

  for (int kt = 0; kt < 16; ++kt) {
    int cur = kt & 1;
    if (kt < 15) STAGE1_ISSUE(kt + 1, (cur ^ 1) * 24576);
    const char* ca = lds + cur * 24576;
    const char* cbp = ca + 16384;
    half8 af[4];
#pragma unroll
    for (int ri = 0; ri < 4; ++ri)
      af[ri] = *(const half8*)(ca + (wave * 4 + ri) * 1024 + lane * 16);
#pragma unroll
    for (int tj = 0; tj < 8; ++tj) {
      half8 b = *(const half8*)(cbp + tj * 1024 + lane * 16);
#pragma unroll
      for (int ri = 0; ri < 4; ++ri)
        acc[ri][tj] = __builtin_amdgcn_mfma_f32_16x16x32_f16(af[ri], b, acc[ri][tj], 0, 0, 0);
    }
    __syncthreads();  // next buffer landed + all reads of cur done
  }
#undef STAGE1_ISSUE

  // Epilogue: d = cn - 2S; per-row top-2 over 128 cols, all in-wave.
  float cn[8]; int coln[8];
#pragma unroll
  for (int tj = 0; tj < 8; ++tj) {
    coln[tj] = n0 + tj * 16 + l15;
    cn[tj] = cnormF[coln[tj]];
  }
#pragma unroll
  for (int ri = 0; ri < 4; ++ri) {
#pragma unroll
    for (int r = 0; r < 4; ++r) {
      unsigned long long k1 = ~0ull, k2 = ~0ull;
#pragma unroll
      for (int tj = 0; tj < 8; ++tj) {
        float v = cn[tj] - 2.0f * acc[ri][tj][r];
        unsigned u = __float_as_uint(v);
        u = (u & 0x80000000u) ? ~u : (u | 0x80000000u);
        unsigned long long key =
            ((unsigned long long)u << 32) | (unsigned)coln[tj];
        if (key < k1) { k2 = k1; k1 = key; }
        else if (key < k2) { k2 = key; }
      }
#pragma unroll
      for (int mask = 1; mask <= 8; mask <<= 1) {
        unsigned long long o1 = __shfl_xor(k1, mask, 64);
        unsigned long long o2 = __shfl_xor(k2, mask, 64);
        if (o1 < k1) { k2 = (k1 < o2) ? k1 : o2; k1 = o1; }
        else { k2 = (k2 < o1) ? k2 : o1; }
      }
      if (l15 == 0) {
        unsigned s1 = (unsigned)(k1 >> 32), s2 = (unsigned)(k2 >> 32);
        unsigned b1 = (s1 & 0x80000000u) ? (s1 ^ 0x80000000u) : ~s1;
        unsigned b2 = (s2 & 0x80000000u) ? (s2 ^ 0x80000000u) : ~s2;
        int row = row0 + wave * 64 + ri * 16 + q * 4 + r;
        cand[(size_t)row * 8 + cbk] = make_float4(
            __uint_as_float(b1), __int_as_float((int)(unsigned)k1),
            __uint_as_float(b2), __int_as_float((int)(unsigned)k2));
      }
    }
  }
}

// ---------------------------------------------------------------------------
// Stage 2: combine 8 chunk top-2s; fp64-refine near-ties (vs fp32 R);
// write id; update residual (row-major R) + staged fp16 Rh16.
// v4: LAST LAYER SKIPS the residual update (R/Rh16 dead after layer NL-1:
// nothing reads them -- saves 80 MB of traffic) and FUSES recon for its 32
// rows (ids for layers 0..NL-2 from idsF, layer NL-1 from sBest; identical
// accumulation order to the old recon_kernel => bitwise-identical output).
// ---------------------------------------------------------------------------
__global__ __launch_bounds__(256) void vq_refine(
    const float* __restrict__ cb, const double* __restrict__ cnorm,
    const float4* __restrict__ cand, float* __restrict__ R,
    unsigned short* __restrict__ Rh16, float* __restrict__ idsF, int layer,
    const float* __restrict__ decW, const float* __restrict__ decb,
    float* __restrict__ recon) {
  __shared__ int sIdx[32][16];
  __shared__ int sCnt[32];
  __shared__ int sBest[32];
  __shared__ int sPair[512];
  __shared__ int sNP;
  __shared__ double sD[32][16];

  int tid = threadIdx.x;
  int b = blockIdx.x;
  // bits [0:2]->v[3:5] (panel), [3:5]->v[0:2], [6:8]->v[6:8]; XCD=b&7=(v>>3)&7
  int v = ((b & 7) << 3) + ((b >> 3) & 7) + ((b >> 6) << 6);
  int row0 = v * 32;

  if (tid == 0) sNP = 0;
  __syncthreads();

  if (tid < 32) {
    int row = row0 + tid;
    float vv[16]; int ix[16];
#pragma unroll
    for (int c = 0; c < 8; ++c) {
      float4 e = cand[(size_t)row * 8 + c];
      vv[2 * c] = e.x;     ix[2 * c] = __float_as_int(e.y);
      vv[2 * c + 1] = e.z; ix[2 * c + 1] = __float_as_int(e.w);
    }
    float M = FLT_MAX; int I = INT_MAX;
#pragma unroll
    for (int p = 0; p < 16; ++p)
      if (vv[p] < M || (vv[p] == M && ix[p] < I)) { M = vv[p]; I = ix[p]; }
    int cnt = 0;
#pragma unroll
    for (int p = 0; p < 16; ++p)
      if (vv[p] < M + DELTA && cnt < 16) sIdx[tid][cnt++] = ix[p];
    sCnt[tid] = cnt;
    sBest[tid] = I;
    if (cnt >= 2) {
      int base = atomicAdd(&sNP, cnt);
      for (int c = 0; c < cnt; ++c) sPair[base + c] = (tid << 4) | c;
    }
  }
  __syncthreads();

  int np = sNP;
  int wave = tid >> 6, lane = tid & 63;
  for (int p = wave; p < np; p += 4) {
    int pr = sPair[p];
    int r = pr >> 4, c = pr & 15;
    int idx = sIdx[r][c];
    const float* rrow = R + (size_t)(row0 + r) * CB;
    const float* crow = cb + (size_t)idx * CB;
    double s = 0.0;
#pragma unroll
    for (int e = 0; e < CB; e += 64)
      s += (double)rrow[e + lane] * (double)crow[e + lane];
#pragma unroll
    for (int off = 32; off > 0; off >>= 1)
      s += __shfl_xor(s, off, 64);
    if (lane == 0) sD[r][c] = cnorm[idx] - 2.0 * s;
  }
  __syncthreads();

  if (tid < 32) {
    int cnt = sCnt[tid];
    if (cnt >= 2) {
      double bestD = 1e300; int bestI = INT_MAX;
      for (int c = 0; c < cnt; ++c) {
        double d = sD[tid][c]; int idx = sIdx[tid][c];
        if (d < bestD || (d == bestD && idx < bestI)) { bestD = d; bestI = idx; }
      }
      sBest[tid] = bestI;
    }
    idsF[(size_t)(row0 + tid) * NL + layer] = (float)sBest[tid];
  }
  __syncthreads();

  if (layer != NL - 1) {
    // residual update: 4 elements per thread per iter
    for (int it = tid; it < 32 * (CB / 4); it += 256) {
      int r = it >> 7, dq = (it & 127) * 4;
      int row = row0 + r;
      size_t o = (size_t)row * CB + dq;
      float4 rv = *(const float4*)(R + o);
      const float* crow = cb + (size_t)sBest[r] * CB + dq;
      float nv[4] = {rv.x - crow[0], rv.y - crow[1], rv.z - crow[2], rv.w - crow[3]};
      *(float4*)(R + o) = make_float4(nv[0], nv[1], nv[2], nv[3]);
      size_t so = staged_off(row, dq);  // dq aligned 4 -> one chunk
      *(ushort4*)(Rh16 + so) =
          make_ushort4(f2h(nv[0]), f2h(nv[1]), f2h(nv[2]), f2h(nv[3]));
    }
  } else {
    // fused recon for this block's 32 rows:
    // recon[row][j] = dec_b[j] + sum_l ids[row][l] * dec_W[l][j]
    // (same accumulation order as the old recon_kernel; layer NL-1 id from
    //  sBest == the float just written to idsF -> bitwise-identical result)
    for (int it = tid; it < 32 * (CB / 4); it += 256) {
      int r = it >> 7, j0 = (it & 127) * 4;
      int row = row0 + r;
      float id3 = (float)sBest[r];
      float out[4];
#pragma unroll
      for (int e = 0; e < 4; ++e) {
        int j = j0 + e;
        float s = decb[j];
#pragma unroll
        for (int l = 0; l < NL - 1; ++l)
          s += idsF[(size_t)row * NL + l] * decW[l * CB + j];
        s += id3 * decW[(NL - 1) * CB + j];
        out[e] = s;
      }
      *(float4*)(recon + (size_t)row * CB + j0) =
          make_float4(out[0], out[1], out[2], out[3]);
    }
  }
}

extern "C" void kernel_launch(void* const* d_in, const int* in_sizes, int n_in,
                              void* d_out, int out_size, void* d_ws, size_t ws_size,
                              hipStream_t stream) {
  const float* X    = (const float*)d_in[0];
  const float* encW = (const float*)d_in[1];
  const float* encb = (const float*)d_in[2];
  const float* cbs  = (const float*)d_in[3];
  const float* decW = (const float*)d_in[4];
  const float* decb = (const float*)d_in[5];

  float* out = (float*)d_out;
  float* recon = out;
  float* idsF = out + (size_t)BB * CB;

  char* ws = (char*)d_ws;
  float* R = (float*)ws;                     ws += (size_t)BB * CB * 4;        // 32 MB
  unsigned short* Rh16 = (unsigned short*)ws; ws += (size_t)BB * CB * 2;       // 16 MB
  unsigned short* Ch16 = (unsigned short*)ws; ws += (size_t)NL * KC * CB * 2;  // 4 MB
  double* cnorm = (double*)ws;               ws += (size_t)NL * KC * 8;        // 32 KB
  float* cnormF = (float*)ws;                ws += (size_t)NL * KC * 4;        // 16 KB
  float4* cand = (float4*)ws;                ws += (size_t)BB * 8 * 16;        // 2 MB
  unsigned short* WTh = (unsigned short*)ws; ws += (size_t)CB * DIN * 2;       // 1 MB
  unsigned short* WTm = (unsigned short*)ws;                                   // 1 MB

  cbsplit_kernel<<<(NL * KC * CB) / 1024, 256, 0, stream>>>(cbs, Ch16);
  cnorm_kernel<<<(NL * KC) / 4, 256, 0, stream>>>(cbs, cnorm, cnormF);
  wsplit_kernel<<<(CB * DIN / 4) / 256, 256, 0, stream>>>(encW, WTh, WTm);
  enc_gemm<<<(BB / 128) * (CB / 128), 256, 0, stream>>>(X, WTh, WTm, encb, R, Rh16);
  for (int l = 0; l < NL; ++l) {
    const float* cbl = cbs + (size_t)l * KC * CB;
    vq_stage1<<<(BB / 256) * 8, 256, 0, stream>>>(
        Rh16, Ch16 + (size_t)l * KC * CB, cnormF + (size_t)l * KC, cand);
    vq_refine<<<BB / 32, 256, 0, stream>>>(cbl, cnorm + (size_t)l * KC, cand,
                                           R, Rh16, idsF, l, decW, decb, recon);
  }
}